// Round 22
// baseline (147.557 us; speedup 1.0000x reference)
//
#include <hip/hip_runtime.h>

#define B_  2
#define S_  512
#define E2_ 512
#define E_  256

#define TT  64    // t-tile per block (stage1)
#define KB  32    // Wp2 slice granularity
#define LDK 264   // padded LDS row stride for sA (528 B, 16B-aligned, balanced banks)

using f32x4 = __attribute__((ext_vector_type(4))) float;
using f16x8 = __attribute__((ext_vector_type(8))) _Float16;

__device__ __forceinline__ float tanh_fast(float x) {
    // NaN-safe: e->inf gives 1-0=1 ; e->0 gives 1-2=-1
    float e = __expf(2.0f * x);
    return 1.0f - 2.0f / (e + 1.0f);
}

// ---- prep: qh f16 copy of q (524288 elems) + Wp2 step-tiled f16 W (131072) -----
__global__ void prep_all(const float* __restrict__ q, _Float16* __restrict__ qh,
                         const float* __restrict__ Wd, _Float16* __restrict__ Wp2) {
    int idx = blockIdx.x * 256 + threadIdx.x;   // 0 .. 131071
    // q -> qh, 4 elems/thread
    float4 v = *(const float4*)(q + idx * 4);
    _Float16 h4[4] = {(_Float16)v.x, (_Float16)v.y, (_Float16)v.z, (_Float16)v.w};
    *(short4*)(qh + idx * 4) = *(short4*)h4;
    // Wd[h][d] -> Wp2[ko][d][kk], 1 elem/thread
    int h = idx >> 8;      // k index 0..511
    int d = idx & 255;     // 0..255
    int ko = h >> 5;
    int kk = h & 31;
    Wp2[ko * (E_ * KB) + d * KB + kk] = (_Float16)Wd[idx];
}

// ---------------- stage1: logits[b,s,t], dense triangular grid -------------------
// 8 t-tiles of 64; 36 unordered tile-pairs (ti<=sj); blockIdx.x = p*64 + sl.
// 4 waves/block (64x64 output quarter each along d). A-products (qt*qs, f16) for a
// 256-wide K-half are mega-staged into LDS in one burst; the 8 K-steps that follow
// run with NO barriers and NO LDS writes (bf L2 loads + af ds_reads + MFMA only).
// 3 barriers total instead of 16.
__global__ __launch_bounds__(256, 4)
void stage1(const _Float16* __restrict__ qh,
            const _Float16* __restrict__ Wp2,
            const float* __restrict__ vd,
            float* __restrict__ logits /* [B*S, S] */) {
    const int x  = blockIdx.x;
    const int p  = x >> 6;          // 0..35
    const int sl = x & 63;
    const int b  = blockIdx.y;
    int sj = 0;
    while ((sj + 1) * (sj + 2) / 2 <= p) ++sj;   // triangular decode
    const int ti = p - sj * (sj + 1) / 2;
    const int s  = sj * TT + sl;
    const int t0 = ti * TT;

    __shared__ _Float16 sA[TT * LDK];      // 33 KiB: qt*qs products, one K-half
    __shared__ _Float16 sQsh[E2_];         // 1 KiB (qh_s row)
    __shared__ float sVd[E_];              // 1 KiB

    const int tid = threadIdx.x;   // 0..255
    {
        const _Float16* qsrow = qh + ((size_t)(b * S_ + s)) * E2_;
        sQsh[tid]       = qsrow[tid];
        sQsh[tid + 256] = qsrow[tid + 256];
        sVd[tid & 255]  = vd[tid & 255];
    }
    __syncthreads();

    const int wave = tid >> 6;    // 0..3
    const int lane = tid & 63;
    const int wd   = wave;        // d-quarter (64 cols)
    const int l15  = lane & 15;
    const int l4   = lane >> 4;   // 0..3

    // A mega-staging: thread -> row = tid>>2 (0..63), k-granule phase kg = tid&3.
    // Per K-half: 8 independent chains of {global b128, lds b128, pk_mul, ds_write}.
    const int a_row = tid >> 2;
    const int kg    = tid & 3;
    const _Float16* qt = qh + ((size_t)(b * S_ + t0 + a_row)) * E2_;

    auto STAGE_HALF = [&](int h2) {
#pragma unroll
        for (int g = 0; g < 8; ++g) {
            int kl = (g * 4 + kg) * 8;                       // 0..248
            f16x8 t = *(const f16x8*)(qt + h2 * 256 + kl);
            f16x8 q = *(const f16x8*)&sQsh[h2 * 256 + kl];
            *(f16x8*)&sA[a_row * LDK + kl] = t * q;          // 4x v_pk_mul_f16
        }
    };

    // B fragments: direct global->reg from compact Wp2 (L2-resident, coalesced 1KB/wave)
    const _Float16* wpb = Wp2 + (wd * 64 + l15) * KB + l4 * 8;   // + fd*16*KB + slice*E_*KB

    f32x4 acc[4][4] = {};

    STAGE_HALF(0);
    asm volatile("s_waitcnt lgkmcnt(0)" ::: "memory");
    __builtin_amdgcn_s_barrier();

#pragma unroll
    for (int h2 = 0; h2 < 2; ++h2) {
        // 8 barrier-free K-steps over this half
#pragma unroll 2
        for (int ko = 0; ko < 8; ++ko) {
            const _Float16* wk = wpb + (h2 * 8 + ko) * (E_ * KB);
            f16x8 bf[4], af[4];
#pragma unroll
            for (int fd = 0; fd < 4; ++fd)
                bf[fd] = *(const f16x8*)(wk + fd * 16 * KB);
#pragma unroll
            for (int ft = 0; ft < 4; ++ft)
                af[ft] = *(const f16x8*)&sA[(ft * 16 + l15) * LDK + ko * 32 + l4 * 8];
            __builtin_amdgcn_s_setprio(1);
#pragma unroll
            for (int ft = 0; ft < 4; ++ft)
#pragma unroll
                for (int fd = 0; fd < 4; ++fd)
                    acc[ft][fd] = __builtin_amdgcn_mfma_f32_16x16x32_f16(af[ft], bf[fd], acc[ft][fd], 0, 0, 0);
            __builtin_amdgcn_s_setprio(0);
        }
        if (h2 == 0) {
            // all reads of half 0 done -> refill with half 1
            asm volatile("s_waitcnt lgkmcnt(0)" ::: "memory");
            __builtin_amdgcn_s_barrier();
            STAGE_HALF(1);
            asm volatile("s_waitcnt lgkmcnt(0)" ::: "memory");
            __builtin_amdgcn_s_barrier();
        }
    }

    __syncthreads();   // all frag reads done -> sA reusable as sRed

    // ---- epilogue: tanh, *vd, reduce over d
    float* sRed = (float*)&sA[0];   // TT*4 floats
    {
        float vdr[4];
#pragma unroll
        for (int fd = 0; fd < 4; ++fd) vdr[fd] = sVd[wd * 64 + fd * 16 + l15];
#pragma unroll
        for (int ft = 0; ft < 4; ++ft) {
#pragma unroll
            for (int r = 0; r < 4; ++r) {
                float pp = 0.f;
#pragma unroll
                for (int fd = 0; fd < 4; ++fd)
                    pp += tanh_fast(acc[ft][fd][r]) * vdr[fd];
                pp += __shfl_xor(pp, 1);
                pp += __shfl_xor(pp, 2);
                pp += __shfl_xor(pp, 4);
                pp += __shfl_xor(pp, 8);
                if (l15 == 0) {
                    int tl = ft * 16 + l4 * 4 + r;
                    sRed[tl * 4 + wd] = pp;
                }
            }
        }
    }
    __syncthreads();
    if (tid < TT) {
        float v = sRed[tid * 4 + 0] + sRed[tid * 4 + 1] + sRed[tid * 4 + 2] + sRed[tid * 4 + 3];
        int t = t0 + tid;
        logits[((size_t)(b * S_ + s)) * S_ + t] = v;   // direct
        logits[((size_t)(b * S_ + t)) * S_ + s] = v;   // mirror (bitwise-identical)
    }
}

// ---------------- softmax in place over rows of 512 ------------------------------
__global__ void softmax_k(float* __restrict__ atten) {
    const int row  = blockIdx.x;
    const int lane = threadIdx.x;
    float* p = atten + (size_t)row * S_;
    float4 v0 = *(float4*)(p + lane * 8);
    float4 v1 = *(float4*)(p + lane * 8 + 4);
    float vv[8] = {v0.x, v0.y, v0.z, v0.w, v1.x, v1.y, v1.z, v1.w};
    float m = vv[0];
#pragma unroll
    for (int j = 1; j < 8; ++j) m = fmaxf(m, vv[j]);
#pragma unroll
    for (int off = 1; off < 64; off <<= 1) m = fmaxf(m, __shfl_xor(m, off));
    float ssum = 0.f;
#pragma unroll
    for (int j = 0; j < 8; ++j) { vv[j] = __expf(vv[j] - m); ssum += vv[j]; }
#pragma unroll
    for (int off = 1; off < 64; off <<= 1) ssum += __shfl_xor(ssum, off);
    float inv = 1.0f / ssum;
    float4 o0 = {vv[0] * inv, vv[1] * inv, vv[2] * inv, vv[3] * inv};
    float4 o1 = {vv[4] * inv, vv[5] * inv, vv[6] * inv, vv[7] * inv};
    *(float4*)(p + lane * 8)     = o0;
    *(float4*)(p + lane * 8 + 4) = o1;
}

// ---------------- context = atten @ value (f32 tiled) -----------------------------
__global__ __launch_bounds__(256)
void context_k(const float* __restrict__ atten, const float* __restrict__ value,
               float* __restrict__ ctx) {
    __shared__ float sA[32][65];
    __shared__ float sV[64][65];
    const int b  = blockIdx.z;
    const int s0 = blockIdx.y * 32;
    const int e0 = blockIdx.x * 64;
    const int tid = threadIdx.x;
    const int ts = tid >> 4;
    const int te = tid & 15;

    float acc[2][4] = {};
    for (int k0 = 0; k0 < S_; k0 += 64) {
        {
            int r = tid >> 3;
            int c = (tid & 7) * 8;
            const float* ga = atten + ((size_t)(b * S_ + s0 + r)) * S_ + k0 + c;
            *(float4*)&sA[r][c]     = *(const float4*)ga;
            *(float4*)&sA[r][c + 4] = *(const float4*)(ga + 4);
        }
        {
            int r = tid >> 2;
            int c = (tid & 3) * 16;
            const float* gv = value + ((size_t)(b * S_ + k0 + r)) * E2_ + e0 + c;
#pragma unroll
            for (int j = 0; j < 16; j += 4)
                *(float4*)&sV[r][c + j] = *(const float4*)(gv + j);
        }
        __syncthreads();
#pragma unroll 8
        for (int kk = 0; kk < 64; ++kk) {
            float a0 = sA[ts * 2 + 0][kk];
            float a1 = sA[ts * 2 + 1][kk];
#pragma unroll
            for (int j = 0; j < 4; ++j) {
                float vvv = sV[kk][te * 4 + j];
                acc[0][j] += a0 * vvv;
                acc[1][j] += a1 * vvv;
            }
        }
        __syncthreads();
    }
#pragma unroll
    for (int i = 0; i < 2; ++i)
#pragma unroll
        for (int j = 0; j < 4; ++j)
            ctx[((size_t)(b * S_ + s0 + ts * 2 + i)) * E2_ + e0 + te * 4 + j] = acc[i][j];
}

extern "C" void kernel_launch(void* const* d_in, const int* in_sizes, int n_in,
                              void* d_out, int out_size, void* d_ws, size_t ws_size,
                              hipStream_t stream) {
    const float* query = (const float*)d_in[0];
    const float* value = (const float*)d_in[1];
    const float* Wd    = (const float*)d_in[2];
    const float* vd    = (const float*)d_in[3];

    float* out   = (float*)d_out;
    float* ctx   = out;                          // [B,S,E2]  (2 MB)
    float* atten = out + (size_t)B_ * S_ * E2_;  // [B,S,S]

    // scratch: qh (1 MB) + Wp2 (256 KB)
    const size_t need = (size_t)(B_ * S_ * E2_ + 16 * E_ * KB) * sizeof(_Float16);
    _Float16* qh;
    if (ws_size >= need) {
        qh = (_Float16*)d_ws;
    } else {
        qh = (_Float16*)ctx;   // 1.25 MB fits in ctx's 2 MB; overwritten by context_k last
    }
    _Float16* wp2 = qh + (size_t)B_ * S_ * E2_;

    prep_all<<<dim3(512), dim3(256), 0, stream>>>(query, qh, Wd, wp2);
    // dense triangular grid: 36 tile-pairs * 64 s-values = 2304 blocks per batch
    stage1<<<dim3(2304, B_), dim3(256), 0, stream>>>(qh, wp2, vd, atten);
    softmax_k<<<dim3(B_ * S_), dim3(64), 0, stream>>>(atten);
    context_k<<<dim3(E2_ / 64, S_ / 32, B_), dim3(256), 0, stream>>>(atten, value, ctx);
}

// Round 23
// 143.500 us; speedup vs baseline: 1.0283x; 1.0283x over previous
//
#include <hip/hip_runtime.h>

#define B_  2
#define S_  512
#define E2_ 512
#define E_  256

#define TT  64    // t-tile per block (stage1)
#define KB  32    // k-tile per step
#define LDK 40    // padded LDS row stride for sA (80 B, 16B-aligned, bank-clean)

using f32x4 = __attribute__((ext_vector_type(4))) float;
using f16x8 = __attribute__((ext_vector_type(8))) _Float16;

__device__ __forceinline__ float tanh_fast(float x) {
    // NaN-safe: e->inf gives 1-0=1 ; e->0 gives 1-2=-1
    float e = __expf(2.0f * x);
    return 1.0f - 2.0f / (e + 1.0f);
}

// ---- prep: qh f16 copy of q (524288 elems) + Wp2 step-tiled f16 W (131072) -----
__global__ void prep_all(const float* __restrict__ q, _Float16* __restrict__ qh,
                         const float* __restrict__ Wd, _Float16* __restrict__ Wp2) {
    int idx = blockIdx.x * 256 + threadIdx.x;   // 0 .. 131071
    // q -> qh, 4 elems/thread
    float4 v = *(const float4*)(q + idx * 4);
    _Float16 h4[4] = {(_Float16)v.x, (_Float16)v.y, (_Float16)v.z, (_Float16)v.w};
    *(short4*)(qh + idx * 4) = *(short4*)h4;
    // Wd[h][d] -> Wp2[ko][d][kk], 1 elem/thread
    int h = idx >> 8;      // k index 0..511
    int d = idx & 255;     // 0..255
    int ko = h >> 5;
    int kk = h & 31;
    Wp2[ko * (E_ * KB) + d * KB + kk] = (_Float16)Wd[idx];
}

// ---------------- stage1: logits[b,s,t], dense triangular grid -------------------
// 8 t-tiles of 64; 36 unordered tile-pairs (ti<=sj); blockIdx.x = p*64 + sl.
// 4 waves/block (64x64 output quarter each along d); qs folded at staging.
// A-products in a 4-SLOT LDS RING: write(slot ko+2) at step ko, read(slot ko) —
// 2 steps of slack means the per-step barrier needs only lgkmcnt(1) (the fresh
// write may stay in flight across it), removing the LDS drain from the barrier.
__global__ __launch_bounds__(256, 4)
void stage1(const _Float16* __restrict__ qh,
            const _Float16* __restrict__ Wp2,
            const float* __restrict__ vd,
            float* __restrict__ logits /* [B*S, S] */) {
    const int x  = blockIdx.x;
    const int p  = x >> 6;          // 0..35
    const int sl = x & 63;
    const int b  = blockIdx.y;
    int sj = 0;
    while ((sj + 1) * (sj + 2) / 2 <= p) ++sj;   // triangular decode
    const int ti = p - sj * (sj + 1) / 2;
    const int s  = sj * TT + sl;
    const int t0 = ti * TT;

    __shared__ _Float16 sA[4][TT * LDK];   // 4 x 5 KiB ring (qt*qs products)
    __shared__ _Float16 sQsh[E2_];         // 1 KiB (qh_s row)
    __shared__ float sVd[E_];              // 1 KiB

    const int tid = threadIdx.x;   // 0..255
    {
        const _Float16* qsrow = qh + ((size_t)(b * S_ + s)) * E2_;
        sQsh[tid]       = qsrow[tid];
        sQsh[tid + 256] = qsrow[tid + 256];
        sVd[tid & 255]  = vd[tid & 255];
    }
    __syncthreads();

    const int wave = tid >> 6;    // 0..3
    const int lane = tid & 63;
    const int wd   = wave;        // d-quarter (64 cols)
    const int l15  = lane & 15;
    const int l4   = lane >> 4;   // 0..3

    // A staging: thread -> row = tid>>2 (0..63), granule = tid&3 (8 f16 each)
    const int a_row = tid >> 2;
    const int a_g   = tid & 3;
    const int a_off = a_row * LDK + a_g * 8;
    const _Float16* qt = qh + ((size_t)(b * S_ + t0 + a_row)) * E2_ + a_g * 8;

    // B fragments: direct global->reg from compact Wp2 (L2-resident, coalesced 1KB/wave)
    const _Float16* wpb = Wp2 + (wd * 64 + l15) * KB + l4 * 8;   // + fd*16*KB + ko*E_*KB

    f16x8 ra0, ra1;                    // A prefetch ping-pong (parity of target step)
    auto AWRITE = [&](int slot, f16x8 ra, int k0) {  // fold qs: sA = qt*qs (f16 RN)
        f16x8 q = *(const f16x8*)&sQsh[k0 + a_g * 8];
        *(f16x8*)&sA[slot][a_off] = ra * q;          // 4x v_pk_mul_f16
    };

    f32x4 acc[4][4] = {};

    // prologue: fill slots 0,1; preload k2 into ra0
    ra0 = *(const f16x8*)(qt + 0 * KB);
    AWRITE(0, ra0, 0 * KB);
    ra1 = *(const f16x8*)(qt + 1 * KB);
    AWRITE(1, ra1, 1 * KB);
    ra0 = *(const f16x8*)(qt + 2 * KB);
    asm volatile("s_waitcnt lgkmcnt(0)" ::: "memory");
    __builtin_amdgcn_s_barrier();

#pragma unroll
    for (int ko = 0; ko < 16; ++ko) {
        const int slot = ko & 3;
        // B frags for THIS step: 4 coalesced global b128 loads (reg-dest)
        f16x8 bf[4];
        {
            const _Float16* wk = wpb + ko * (E_ * KB);
#pragma unroll
            for (int fd = 0; fd < 4; ++fd)
                bf[fd] = *(const f16x8*)(wk + fd * 16 * KB);
        }
        // A frags: already-folded products (slot guarded by barrier(ko-1))
        f16x8 af[4];
#pragma unroll
        for (int ft = 0; ft < 4; ++ft) {
            int row = ft * 16 + l15;
            af[ft] = *(const f16x8*)&sA[slot][row * LDK + l4 * 8];
        }
        // ring maintenance: write slot ko+2 from ra[ko&1]; load k(ko+3) into ra[(ko+1)&1]
        if (ko <= 13) AWRITE((ko + 2) & 3, (ko & 1) ? ra1 : ra0, (ko + 2) * KB);
        if (ko <= 12) {
            if ((ko + 3) & 1) ra1 = *(const f16x8*)(qt + (ko + 3) * KB);
            else              ra0 = *(const f16x8*)(qt + (ko + 3) * KB);
        }
        __builtin_amdgcn_s_setprio(1);
#pragma unroll
        for (int ft = 0; ft < 4; ++ft)
#pragma unroll
            for (int fd = 0; fd < 4; ++fd)
                acc[ft][fd] = __builtin_amdgcn_mfma_f32_16x16x32_f16(af[ft], bf[fd], acc[ft][fd], 0, 0, 0);
        __builtin_amdgcn_s_setprio(0);
        if (ko <= 13) {
            // fresh write may stay in flight; it retires before the NEXT barrier,
            // which is what guards its readers (2-step slack)
            asm volatile("s_waitcnt lgkmcnt(1)" ::: "memory");
            __builtin_amdgcn_s_barrier();
        } else if (ko == 14) {
            asm volatile("s_waitcnt lgkmcnt(0)" ::: "memory");
            __builtin_amdgcn_s_barrier();
        }
    }

    __syncthreads();   // all frag reads done -> sA reusable as sRed

    // ---- epilogue: tanh, *vd, reduce over d
    float* sRed = (float*)&sA[0][0];   // TT*4 floats
    {
        float vdr[4];
#pragma unroll
        for (int fd = 0; fd < 4; ++fd) vdr[fd] = sVd[wd * 64 + fd * 16 + l15];
#pragma unroll
        for (int ft = 0; ft < 4; ++ft) {
#pragma unroll
            for (int r = 0; r < 4; ++r) {
                float pp = 0.f;
#pragma unroll
                for (int fd = 0; fd < 4; ++fd)
                    pp += tanh_fast(acc[ft][fd][r]) * vdr[fd];
                pp += __shfl_xor(pp, 1);
                pp += __shfl_xor(pp, 2);
                pp += __shfl_xor(pp, 4);
                pp += __shfl_xor(pp, 8);
                if (l15 == 0) {
                    int tl = ft * 16 + l4 * 4 + r;
                    sRed[tl * 4 + wd] = pp;
                }
            }
        }
    }
    __syncthreads();
    if (tid < TT) {
        float v = sRed[tid * 4 + 0] + sRed[tid * 4 + 1] + sRed[tid * 4 + 2] + sRed[tid * 4 + 3];
        int t = t0 + tid;
        logits[((size_t)(b * S_ + s)) * S_ + t] = v;   // direct
        logits[((size_t)(b * S_ + t)) * S_ + s] = v;   // mirror (bitwise-identical)
    }
}

// ---------------- softmax in place over rows of 512 ------------------------------
__global__ void softmax_k(float* __restrict__ atten) {
    const int row  = blockIdx.x;
    const int lane = threadIdx.x;
    float* p = atten + (size_t)row * S_;
    float4 v0 = *(float4*)(p + lane * 8);
    float4 v1 = *(float4*)(p + lane * 8 + 4);
    float vv[8] = {v0.x, v0.y, v0.z, v0.w, v1.x, v1.y, v1.z, v1.w};
    float m = vv[0];
#pragma unroll
    for (int j = 1; j < 8; ++j) m = fmaxf(m, vv[j]);
#pragma unroll
    for (int off = 1; off < 64; off <<= 1) m = fmaxf(m, __shfl_xor(m, off));
    float ssum = 0.f;
#pragma unroll
    for (int j = 0; j < 8; ++j) { vv[j] = __expf(vv[j] - m); ssum += vv[j]; }
#pragma unroll
    for (int off = 1; off < 64; off <<= 1) ssum += __shfl_xor(ssum, off);
    float inv = 1.0f / ssum;
    float4 o0 = {vv[0] * inv, vv[1] * inv, vv[2] * inv, vv[3] * inv};
    float4 o1 = {vv[4] * inv, vv[5] * inv, vv[6] * inv, vv[7] * inv};
    *(float4*)(p + lane * 8)     = o0;
    *(float4*)(p + lane * 8 + 4) = o1;
}

// ---------------- context = atten @ value (f32 tiled) -----------------------------
__global__ __launch_bounds__(256)
void context_k(const float* __restrict__ atten, const float* __restrict__ value,
               float* __restrict__ ctx) {
    __shared__ float sA[32][65];
    __shared__ float sV[64][65];
    const int b  = blockIdx.z;
    const int s0 = blockIdx.y * 32;
    const int e0 = blockIdx.x * 64;
    const int tid = threadIdx.x;
    const int ts = tid >> 4;
    const int te = tid & 15;

    float acc[2][4] = {};
    for (int k0 = 0; k0 < S_; k0 += 64) {
        {
            int r = tid >> 3;
            int c = (tid & 7) * 8;
            const float* ga = atten + ((size_t)(b * S_ + s0 + r)) * S_ + k0 + c;
            *(float4*)&sA[r][c]     = *(const float4*)ga;
            *(float4*)&sA[r][c + 4] = *(const float4*)(ga + 4);
        }
        {
            int r = tid >> 2;
            int c = (tid & 3) * 16;
            const float* gv = value + ((size_t)(b * S_ + k0 + r)) * E2_ + e0 + c;
#pragma unroll
            for (int j = 0; j < 16; j += 4)
                *(float4*)&sV[r][c + j] = *(const float4*)(gv + j);
        }
        __syncthreads();
#pragma unroll 8
        for (int kk = 0; kk < 64; ++kk) {
            float a0 = sA[ts * 2 + 0][kk];
            float a1 = sA[ts * 2 + 1][kk];
#pragma unroll
            for (int j = 0; j < 4; ++j) {
                float vvv = sV[kk][te * 4 + j];
                acc[0][j] += a0 * vvv;
                acc[1][j] += a1 * vvv;
            }
        }
        __syncthreads();
    }
#pragma unroll
    for (int i = 0; i < 2; ++i)
#pragma unroll
        for (int j = 0; j < 4; ++j)
            ctx[((size_t)(b * S_ + s0 + ts * 2 + i)) * E2_ + e0 + te * 4 + j] = acc[i][j];
}

extern "C" void kernel_launch(void* const* d_in, const int* in_sizes, int n_in,
                              void* d_out, int out_size, void* d_ws, size_t ws_size,
                              hipStream_t stream) {
    const float* query = (const float*)d_in[0];
    const float* value = (const float*)d_in[1];
    const float* Wd    = (const float*)d_in[2];
    const float* vd    = (const float*)d_in[3];

    float* out   = (float*)d_out;
    float* ctx   = out;                          // [B,S,E2]  (2 MB)
    float* atten = out + (size_t)B_ * S_ * E2_;  // [B,S,S]

    // scratch: qh (1 MB) + Wp2 (256 KB)
    const size_t need = (size_t)(B_ * S_ * E2_ + 16 * E_ * KB) * sizeof(_Float16);
    _Float16* qh;
    if (ws_size >= need) {
        qh = (_Float16*)d_ws;
    } else {
        qh = (_Float16*)ctx;   // 1.25 MB fits in ctx's 2 MB; overwritten by context_k last
    }
    _Float16* wp2 = qh + (size_t)B_ * S_ * E2_;

    prep_all<<<dim3(512), dim3(256), 0, stream>>>(query, qh, Wd, wp2);
    // dense triangular grid: 36 tile-pairs * 64 s-values = 2304 blocks per batch
    stage1<<<dim3(2304, B_), dim3(256), 0, stream>>>(qh, wp2, vd, atten);
    softmax_k<<<dim3(B_ * S_), dim3(64), 0, stream>>>(atten);
    context_k<<<dim3(E2_ / 64, S_ / 32, B_), dim3(256), 0, stream>>>(atten, value, ctx);
}

// Round 24
// 140.279 us; speedup vs baseline: 1.0519x; 1.0230x over previous
//
#include <hip/hip_runtime.h>

#define B_  2
#define S_  512
#define E2_ 512
#define E_  256

#define TT  64    // t-tile per block (stage1)
#define KB  32    // k-tile per step
#define LDK 40    // padded LDS row stride for sA (80 B, 16B-aligned, bank-clean)

using f32x4 = __attribute__((ext_vector_type(4))) float;
using f16x8 = __attribute__((ext_vector_type(8))) _Float16;

__device__ __forceinline__ float tanh_fast(float x) {
    // NaN-safe: e->inf gives 1-0=1 ; e->0 gives 1-2=-1
    float e = __expf(2.0f * x);
    return 1.0f - 2.0f / (e + 1.0f);
}

#define SBAR() __builtin_amdgcn_sched_barrier(0)

// ---- prep: qh f16 copy of q (524288 elems) + Wp2 step-tiled f16 W (131072) -----
__global__ void prep_all(const float* __restrict__ q, _Float16* __restrict__ qh,
                         const float* __restrict__ Wd, _Float16* __restrict__ Wp2) {
    int idx = blockIdx.x * 256 + threadIdx.x;   // 0 .. 131071
    // q -> qh, 4 elems/thread
    float4 v = *(const float4*)(q + idx * 4);
    _Float16 h4[4] = {(_Float16)v.x, (_Float16)v.y, (_Float16)v.z, (_Float16)v.w};
    *(short4*)(qh + idx * 4) = *(short4*)h4;
    // Wd[h][d] -> Wp2[ko][d][kk], 1 elem/thread
    int h = idx >> 8;      // k index 0..511
    int d = idx & 255;     // 0..255
    int ko = h >> 5;
    int kk = h & 31;
    Wp2[ko * (E_ * KB) + d * KB + kk] = (_Float16)Wd[idx];
}

// ---------------- stage1: logits[b,s,t], dense triangular grid -------------------
// 8 t-tiles of 64; 36 unordered tile-pairs (ti<=sj); blockIdx.x = p*64 + sl.
// 4 waves/block (one 64x64 output quarter each along d); qs folded at staging
// (bitwise-identical numerics) so the MFMA consume path is ds_read -> MFMA only.
// No setprio: lockstep 4-wave blocks match m190's regime where it is null/negative.
__global__ __launch_bounds__(256, 4)
void stage1(const _Float16* __restrict__ qh,
            const _Float16* __restrict__ Wp2,
            const float* __restrict__ vd,
            float* __restrict__ logits /* [B*S, S] */) {
    const int x  = blockIdx.x;
    const int p  = x >> 6;          // 0..35
    const int sl = x & 63;
    const int b  = blockIdx.y;
    int sj = 0;
    while ((sj + 1) * (sj + 2) / 2 <= p) ++sj;   // triangular decode
    const int ti = p - sj * (sj + 1) / 2;
    const int s  = sj * TT + sl;
    const int t0 = ti * TT;

    __shared__ _Float16 sA[2][TT * LDK];   // 2 x 5 KiB (qt*qs products)
    __shared__ _Float16 sQsh[E2_];         // 1 KiB (qh_s row)
    __shared__ float sVd[E_];              // 1 KiB

    const int tid = threadIdx.x;   // 0..255
    {
        const _Float16* qsrow = qh + ((size_t)(b * S_ + s)) * E2_;
        sQsh[tid]       = qsrow[tid];
        sQsh[tid + 256] = qsrow[tid + 256];
        sVd[tid & 255]  = vd[tid & 255];
    }
    __syncthreads();

    const int wave = tid >> 6;    // 0..3
    const int lane = tid & 63;
    const int wd   = wave;        // d-quarter (64 cols)
    const int l15  = lane & 15;
    const int l4   = lane >> 4;   // 0..3

    // A staging: thread -> row = tid>>2 (0..63), granule = tid&3 (8 f16 each)
    const int a_row = tid >> 2;
    const int a_g   = tid & 3;
    const int a_off = a_row * LDK + a_g * 8;
    const _Float16* qt = qh + ((size_t)(b * S_ + t0 + a_row)) * E2_ + a_g * 8;

    // B fragments: direct global->reg from compact Wp2 (L2-resident, coalesced 1KB/wave)
    const _Float16* wpb = Wp2 + (wd * 64 + l15) * KB + l4 * 8;   // + fd*16*KB + ko*E_*KB

    f16x8 ra;                          // A prefetch register (pure qt copy)
    auto ALOAD  = [&](int k0) { ra = *(const f16x8*)(qt + k0); };
    auto AWRITE = [&](int k0, int hh) {    // fold qs at staging: sA = qt*qs (f16 RN)
        f16x8 q = *(const f16x8*)&sQsh[k0 + a_g * 8];
        *(f16x8*)&sA[hh][a_off] = ra * q;  // 4x v_pk_mul_f16, off the consume path
    };

    f32x4 acc[4][4] = {};

    // prologue
    ALOAD(0);
    SBAR();
    AWRITE(0, 0);          // compiler inserts exact vmcnt wait for ra
    SBAR();
    ALOAD(KB);             // stays in flight across the barrier
    SBAR();
    asm volatile("s_waitcnt lgkmcnt(0)" ::: "memory");
    __builtin_amdgcn_s_barrier();
    SBAR();

    for (int ko = 0; ko < E2_ / KB; ++ko) {
        const int h = ko & 1;
        // B frags for THIS step: 4 coalesced global b128 loads (reg-dest)
        f16x8 bf[4];
        {
            const _Float16* wk = wpb + ko * (E_ * KB);
#pragma unroll
            for (int fd = 0; fd < 4; ++fd)
                bf[fd] = *(const f16x8*)(wk + fd * 16 * KB);
        }
        SBAR();
        // A frags: already-folded products, straight into MFMA
        f16x8 af[4];
#pragma unroll
        for (int ft = 0; ft < 4; ++ft) {
            int row = ft * 16 + l15;
            af[ft] = *(const f16x8*)&sA[h][row * LDK + l4 * 8];
        }
        SBAR();
        if (ko < 15) { AWRITE((ko + 1) * KB, h ^ 1); SBAR(); }   // uses ra from prev ALOAD
        if (ko < 14) { ALOAD((ko + 2) * KB); SBAR(); }           // reg-dest, spans barrier
        if (ko < 15) {
            asm volatile("s_waitcnt lgkmcnt(0)" ::: "memory");   // LDS ops drained
            __builtin_amdgcn_s_barrier();
            SBAR();
        }
#pragma unroll
        for (int ft = 0; ft < 4; ++ft)
#pragma unroll
            for (int fd = 0; fd < 4; ++fd)
                acc[ft][fd] = __builtin_amdgcn_mfma_f32_16x16x32_f16(af[ft], bf[fd], acc[ft][fd], 0, 0, 0);
    }

    __syncthreads();   // all frag reads done -> sA reusable as sRed

    // ---- epilogue: tanh, *vd, reduce over d
    float* sRed = (float*)&sA[0][0];   // TT*4 floats
    {
        float vdr[4];
#pragma unroll
        for (int fd = 0; fd < 4; ++fd) vdr[fd] = sVd[wd * 64 + fd * 16 + l15];
#pragma unroll
        for (int ft = 0; ft < 4; ++ft) {
#pragma unroll
            for (int r = 0; r < 4; ++r) {
                float pp = 0.f;
#pragma unroll
                for (int fd = 0; fd < 4; ++fd)
                    pp += tanh_fast(acc[ft][fd][r]) * vdr[fd];
                pp += __shfl_xor(pp, 1);
                pp += __shfl_xor(pp, 2);
                pp += __shfl_xor(pp, 4);
                pp += __shfl_xor(pp, 8);
                if (l15 == 0) {
                    int tl = ft * 16 + l4 * 4 + r;
                    sRed[tl * 4 + wd] = pp;
                }
            }
        }
    }
    __syncthreads();
    if (tid < TT) {
        float v = sRed[tid * 4 + 0] + sRed[tid * 4 + 1] + sRed[tid * 4 + 2] + sRed[tid * 4 + 3];
        int t = t0 + tid;
        logits[((size_t)(b * S_ + s)) * S_ + t] = v;   // direct
        logits[((size_t)(b * S_ + t)) * S_ + s] = v;   // mirror (bitwise-identical)
    }
}

// ---------------- softmax in place over rows of 512 ------------------------------
__global__ void softmax_k(float* __restrict__ atten) {
    const int row  = blockIdx.x;
    const int lane = threadIdx.x;
    float* p = atten + (size_t)row * S_;
    float4 v0 = *(float4*)(p + lane * 8);
    float4 v1 = *(float4*)(p + lane * 8 + 4);
    float vv[8] = {v0.x, v0.y, v0.z, v0.w, v1.x, v1.y, v1.z, v1.w};
    float m = vv[0];
#pragma unroll
    for (int j = 1; j < 8; ++j) m = fmaxf(m, vv[j]);
#pragma unroll
    for (int off = 1; off < 64; off <<= 1) m = fmaxf(m, __shfl_xor(m, off));
    float ssum = 0.f;
#pragma unroll
    for (int j = 0; j < 8; ++j) { vv[j] = __expf(vv[j] - m); ssum += vv[j]; }
#pragma unroll
    for (int off = 1; off < 64; off <<= 1) ssum += __shfl_xor(ssum, off);
    float inv = 1.0f / ssum;
    float4 o0 = {vv[0] * inv, vv[1] * inv, vv[2] * inv, vv[3] * inv};
    float4 o1 = {vv[4] * inv, vv[5] * inv, vv[6] * inv, vv[7] * inv};
    *(float4*)(p + lane * 8)     = o0;
    *(float4*)(p + lane * 8 + 4) = o1;
}

// ---------------- context = atten @ value (f32 tiled) -----------------------------
__global__ __launch_bounds__(256)
void context_k(const float* __restrict__ atten, const float* __restrict__ value,
               float* __restrict__ ctx) {
    __shared__ float sA[32][65];
    __shared__ float sV[64][65];
    const int b  = blockIdx.z;
    const int s0 = blockIdx.y * 32;
    const int e0 = blockIdx.x * 64;
    const int tid = threadIdx.x;
    const int ts = tid >> 4;
    const int te = tid & 15;

    float acc[2][4] = {};
    for (int k0 = 0; k0 < S_; k0 += 64) {
        {
            int r = tid >> 3;
            int c = (tid & 7) * 8;
            const float* ga = atten + ((size_t)(b * S_ + s0 + r)) * S_ + k0 + c;
            *(float4*)&sA[r][c]     = *(const float4*)ga;
            *(float4*)&sA[r][c + 4] = *(const float4*)(ga + 4);
        }
        {
            int r = tid >> 2;
            int c = (tid & 3) * 16;
            const float* gv = value + ((size_t)(b * S_ + k0 + r)) * E2_ + e0 + c;
#pragma unroll
            for (int j = 0; j < 16; j += 4)
                *(float4*)&sV[r][c + j] = *(const float4*)(gv + j);
        }
        __syncthreads();
#pragma unroll 8
        for (int kk = 0; kk < 64; ++kk) {
            float a0 = sA[ts * 2 + 0][kk];
            float a1 = sA[ts * 2 + 1][kk];
#pragma unroll
            for (int j = 0; j < 4; ++j) {
                float vvv = sV[kk][te * 4 + j];
                acc[0][j] += a0 * vvv;
                acc[1][j] += a1 * vvv;
            }
        }
        __syncthreads();
    }
#pragma unroll
    for (int i = 0; i < 2; ++i)
#pragma unroll
        for (int j = 0; j < 4; ++j)
            ctx[((size_t)(b * S_ + s0 + ts * 2 + i)) * E2_ + e0 + te * 4 + j] = acc[i][j];
}

extern "C" void kernel_launch(void* const* d_in, const int* in_sizes, int n_in,
                              void* d_out, int out_size, void* d_ws, size_t ws_size,
                              hipStream_t stream) {
    const float* query = (const float*)d_in[0];
    const float* value = (const float*)d_in[1];
    const float* Wd    = (const float*)d_in[2];
    const float* vd    = (const float*)d_in[3];

    float* out   = (float*)d_out;
    float* ctx   = out;                          // [B,S,E2]  (2 MB)
    float* atten = out + (size_t)B_ * S_ * E2_;  // [B,S,S]

    // scratch: qh (1 MB) + Wp2 (256 KB)
    const size_t need = (size_t)(B_ * S_ * E2_ + 16 * E_ * KB) * sizeof(_Float16);
    _Float16* qh;
    if (ws_size >= need) {
        qh = (_Float16*)d_ws;
    } else {
        qh = (_Float16*)ctx;   // 1.25 MB fits in ctx's 2 MB; overwritten by context_k last
    }
    _Float16* wp2 = qh + (size_t)B_ * S_ * E2_;

    prep_all<<<dim3(512), dim3(256), 0, stream>>>(query, qh, Wd, wp2);
    // dense triangular grid: 36 tile-pairs * 64 s-values = 2304 blocks per batch
    stage1<<<dim3(2304, B_), dim3(256), 0, stream>>>(qh, wp2, vd, atten);
    softmax_k<<<dim3(B_ * S_), dim3(64), 0, stream>>>(atten);
    context_k<<<dim3(E2_ / 64, S_ / 32, B_), dim3(256), 0, stream>>>(atten, value, ctx);
}